// Round 14
// baseline (16.893 us; speedup 1.0000x reference)
//
#include <hip/hip_runtime.h>
#include <math.h>

namespace {
constexpr int Bn = 8192, Pn = 128, Dn = 128;
constexpr int BT = 64, PT = 32;                   // block tile: 64 b x 32 p
constexpr float MAXN = 1.0f - 1e-5f;              // (1-PROJ_EPS)/sqrt(c)
constexpr float CLAMPV = 16.63553233343869f;      // log(2/eps32)
constexpr float SMOOTH = 50.0f;
}

typedef float f2 __attribute__((ext_vector_type(2)));

#if defined(__has_builtin)
#if __has_builtin(__builtin_elementwise_fma)
#define FMA2(a, b, c) __builtin_elementwise_fma((a), (b), (c))
#else
static __device__ __forceinline__ f2 FMA2(f2 a, f2 b, f2 c) {
  c.x = fmaf(a.x, b.x, c.x); c.y = fmaf(a.y, b.y, c.y); return c;
}
#endif
#else
static __device__ __forceinline__ f2 FMA2(f2 a, f2 b, f2 c) {
  c.x = fmaf(a.x, b.x, c.x); c.y = fmaf(a.y, b.y, c.y); return c;
}
#endif

// ---------------- single fused kernel, 256 threads (4 waves = 4 k-teams) ------
// LDS union lds4[3072] f4 (48 KB):
//   phase A: 0..2047 x-tile (XOR swizzled); 2048..2431 p-partials; 2432..2687 x-partials
//   phase B: 0..2047 x-tile; 2048..3071 v-tile (over dead scratch)
//   phase C: 0..2047 park [team][txp][i][tyy]
// ~50KB total -> 3 blocks/CU = 12 waves/CU.
__global__ __launch_bounds__(256, 3)
void fused_kernel(const float* __restrict__ x,
                  const float* __restrict__ weight,
                  const float* __restrict__ bias,
                  float* __restrict__ out) {
  __shared__ float4 lds4[3072];
  __shared__ double psum[96];
  __shared__ float x2A[64], fbA[64];
  __shared__ float bwA[32], iaA[32], soA[32];

  float* const scpf = reinterpret_cast<float*>(lds4 + 2048);  // 6*256 f32
  float* const scxf = reinterpret_cast<float*>(lds4 + 2432);  // 4*256 f32

  const int tid = threadIdx.x;
  const int team = tid >> 6;            // 0..3 : k-quarter (== wave id)
  const int ti = tid & 63;
  const int txp = ti & 7;               // p-group (4 p-cols)
  const int tyy = ti >> 3;              // b-group (8 rows), 0..7
  const int b0 = blockIdx.x * BT;
  const int p0 = blockIdx.y * PT;
  const int rr16 = tid >> 4;            // 0..15
  const int cc16 = tid & 15;            // 0..15

  // ---- global loads (coalesced: 16 lanes span 256B row segments)
  float4 xv[4][2], wv[2][2], bv[2][2];
#pragma unroll
  for (int q = 0; q < 4; ++q)
#pragma unroll
    for (int h = 0; h < 2; ++h)
      xv[q][h] = *reinterpret_cast<const float4*>(
          x + (size_t)(b0 + 16 * q + rr16) * Dn + (cc16 + 16 * h) * 4);
#pragma unroll
  for (int q = 0; q < 2; ++q)
#pragma unroll
    for (int h = 0; h < 2; ++h) {
      wv[q][h] = *reinterpret_cast<const float4*>(
          weight + (size_t)(p0 + 16 * q + rr16) * Dn + (cc16 + 16 * h) * 4);
      bv[q][h] = *reinterpret_cast<const float4*>(
          bias + (size_t)(p0 + 16 * q + rr16) * Dn + (cc16 + 16 * h) * 4);
    }

  // ---- stage x tile (swizzled) + f32 stat partials
#pragma unroll
  for (int q = 0; q < 4; ++q) {
    const int r = 16 * q + rr16;
    const int s = (r >> 2) & 7;
    float xs2 = 0.0f;
#pragma unroll
    for (int h = 0; h < 2; ++h) {
      const int c = cc16 + 16 * h;
      lds4[r * 32 + (c ^ s)] = xv[q][h];
      float4 v = xv[q][h];
      xs2 += fmaf(v.x, v.x, fmaf(v.y, v.y, fmaf(v.z, v.z, v.w * v.w)));
    }
    scxf[q * 256 + tid] = xs2;
  }
#pragma unroll
  for (int q = 0; q < 2; ++q) {
    float nb2 = 0.f, bwd = 0.f, w2 = 0.f;
#pragma unroll
    for (int h = 0; h < 2; ++h) {
      float4 w = wv[q][h], b = bv[q][h];
      nb2 += fmaf(b.x, b.x, fmaf(b.y, b.y, fmaf(b.z, b.z, b.w * b.w)));
      bwd += fmaf(b.x, w.x, fmaf(b.y, w.y, fmaf(b.z, w.z, b.w * w.w)));
      w2  += fmaf(w.x, w.x, fmaf(w.y, w.y, fmaf(w.z, w.z, w.w * w.w)));
    }
    scpf[(q * 3 + 0) * 256 + tid] = nb2;
    scpf[(q * 3 + 1) * 256 + tid] = bwd;
    scpf[(q * 3 + 2) * 256 + tid] = w2;
  }
  __syncthreads();

  // ---- trees (rotated reads; f64 accumulate)
  if (tid < 96) {
    const int row = tid / 3;
    const int val = tid - 3 * row;
    const float4* base = lds4 + 2048 + ((row >> 4) * 3 + val) * 64 + (row & 15) * 4;
    double s = 0.0;
#pragma unroll
    for (int k = 0; k < 4; ++k) {
      float4 f = base[(k + tid) & 3];
      s += (double)f.x + (double)f.y + (double)f.z + (double)f.w;
    }
    psum[tid] = s;
  } else if (tid >= 128 && tid < 192) {
    const int r = tid - 128;
    const float4* base = lds4 + 2432 + (r >> 4) * 64 + (r & 15) * 4;
    double s = 0.0;
#pragma unroll
    for (int k = 0; k < 4; ++k) {
      float4 f = base[(k + tid) & 3];
      s += (double)f.x + (double)f.y + (double)f.z + (double)f.w;
    }
    x2A[r] = (float)s;
    fbA[r] = (float)(2.0 / (1.0 - s));
  }
  __syncthreads();

  // ---- v-build (v = cx*w + k2*bias; f64 cancellation island)
#pragma unroll
  for (int q = 0; q < 2; ++q) {
    const int r = 16 * q + rr16;
    double nb2 = psum[3 * r + 0];
    double bwd = psum[3 * r + 1];
    double w2  = psum[3 * r + 2];
    double norm = sqrt(nb2);
    if (norm < 1e-15) norm = 1e-15;
    double scl = (norm > (double)MAXN) ? (double)MAXN / norm : 1.0;
    double p2 = nb2 * scl * scl;
    const float cxf = (float)(1.0 - p2);
    const float bwf = (float)(scl * bwd);
    const float k2f = 2.0f * bwf * (float)scl;
    const int s = (r >> 2) & 7;
#pragma unroll
    for (int h = 0; h < 2; ++h) {
      float4 w = wv[q][h], b = bv[q][h], v;
      v.x = fmaf(cxf, w.x, k2f * b.x);
      v.y = fmaf(cxf, w.y, k2f * b.y);
      v.z = fmaf(cxf, w.z, k2f * b.z);
      v.w = fmaf(cxf, w.w, k2f * b.w);
      lds4[2048 + r * 32 + ((cc16 + 16 * h) ^ s)] = v;
    }
    if (cc16 == 0) {
      float an = cxf * sqrtf((float)w2);
      if (an < 1e-15f) an = 1e-15f;
      bwA[r] = bwf;
      iaA[r] = 1.0f / an;
      soA[r] = 2.0f / cxf * an;           // lambda_p * a_norm
    }
  }
  __syncthreads();

  // ---- GEMM: micro 8(b) x 4(p), wave = k-team (8 k4-steps), packed FMA
  f2 acc2[8][4];
#pragma unroll
  for (int i = 0; i < 8; ++i)
#pragma unroll
    for (int j = 0; j < 4; ++j) acc2[i][j] = f2{0.0f, 0.0f};

#pragma unroll 2
  for (int kb = 0; kb < 8; ++kb) {
    const int k4 = team * 8 + kb;
    f2 vlo[4], vhi[4];
#pragma unroll
    for (int j = 0; j < 4; ++j) {
      float4 vf = lds4[2048 + (4 * txp + j) * 32 + (k4 ^ txp)];
      vlo[j] = f2{vf.x, vf.y};
      vhi[j] = f2{vf.z, vf.w};
    }
#pragma unroll
    for (int i = 0; i < 8; ++i) {
      const int r = 8 * tyy + i;
      float4 xf = lds4[r * 32 + (k4 ^ ((r >> 2) & 7))];
      f2 xlo = f2{xf.x, xf.y};
      f2 xhi = f2{xf.z, xf.w};
#pragma unroll
      for (int j = 0; j < 4; ++j) {
        acc2[i][j] = FMA2(xlo, vlo[j], acc2[i][j]);
        acc2[i][j] = FMA2(xhi, vhi[j], acc2[i][j]);
      }
    }
  }
  __syncthreads();

  // ---- park 4 k-partials into dead x region: [team][txp][i][tyy]
#pragma unroll
  for (int i = 0; i < 8; ++i) {
    lds4[team * 512 + txp * 64 + i * 8 + tyy] =
        make_float4(acc2[i][0].x + acc2[i][0].y, acc2[i][1].x + acc2[i][1].y,
                    acc2[i][2].x + acc2[i][2].y, acc2[i][3].x + acc2[i][3].y);
  }
  __syncthreads();

  // ---- merge + epilogue: thread owns (row = tid&63, 2 f4 p-cols)
  {
    const int row = tid & 63;
    const int pgh = tid >> 6;             // 0..3
    const float x2i = x2A[row];
    const float fbi = fbA[row];
    const float opx = 1.0f + x2i;
#pragma unroll
    for (int u = 0; u < 2; ++u) {
      const int cpg = pgh * 2 + u;        // f4 p-col 0..7
      float s[4] = {0.f, 0.f, 0.f, 0.f};
#pragma unroll
      for (int t = 0; t < 4; ++t) {
        float4 pp4 = lds4[t * 512 + cpg * 64 + (row & 7) * 8 + (row >> 3)];
        s[0] += pp4.x; s[1] += pp4.y; s[2] += pp4.z; s[3] += pp4.w;
      }
      float res[4];
#pragma unroll
      for (int j = 0; j < 4; ++j) {
        const int pl = cpg * 4 + j;
        float X = fmaf(-opx, bwA[pl], s[j]);       // <x,v> - (1+x2)*bw
        float arg = X * fbi * iaA[pl];             // Mobius denominator cancels
        float aa = fabsf(arg);
        float argc;
        if (aa <= CLAMPV - 0.35f) {
          argc = aa;                               // smooth_clamp == identity (exact)
        } else if (aa >= CLAMPV + 0.35f) {
          argc = CLAMPV;                           // fully clamped (exact)
        } else {
          float z = SMOOTH * (aa - CLAMPV);        // band: softplus correction
          float sp = (fmaxf(z, 0.0f) + log1pf(__expf(-fabsf(z)))) * (1.0f / SMOOTH);
          argc = aa - sp;
        }
        float r = __logf(argc + sqrtf(fmaf(argc, argc, 1.0f)));  // asinh, z>=0
        res[j] = copysignf(soA[pl] * r, arg);
      }
      *reinterpret_cast<float4*>(out + (size_t)(b0 + row) * Pn + p0 + cpg * 4) =
          make_float4(res[0], res[1], res[2], res[3]);
    }
  }
}

extern "C" void kernel_launch(void* const* d_in, const int* in_sizes, int n_in,
                              void* d_out, int out_size, void* d_ws, size_t ws_size,
                              hipStream_t stream) {
  const float* x = (const float*)d_in[0];
  const float* w = (const float*)d_in[1];
  const float* bias = (const float*)d_in[2];
  float* out = (float*)d_out;

  hipLaunchKernelGGL(fused_kernel, dim3(Bn / BT, Pn / PT), dim3(256), 0, stream,
                     x, w, bias, out);
}

// Round 15
// 14.081 us; speedup vs baseline: 1.1997x; 1.1997x over previous
//
#include <hip/hip_runtime.h>
#include <math.h>

namespace {
constexpr int Bn = 8192, Pn = 128, Dn = 128;
constexpr int BT = 64, PT = 32;                   // block tile: 64 b x 32 p
constexpr float MAXN = 1.0f - 1e-5f;              // (1-PROJ_EPS)/sqrt(c)
constexpr float CLAMPV = 16.63553233343869f;      // log(2/eps32)
constexpr float SMOOTH = 50.0f;
}

typedef short bf8 __attribute__((ext_vector_type(8)));    // 8 bf16 (MFMA A/B frag)
typedef float f32x4 __attribute__((ext_vector_type(4)));  // MFMA C/D frag

__device__ __forceinline__ unsigned short bf16rn(float f) {
  unsigned int u = __float_as_uint(f);
  u = u + 0x7fffu + ((u >> 16) & 1u);             // round-to-nearest-even
  return (unsigned short)(u >> 16);
}
__device__ __forceinline__ float bf2f(unsigned short h) {
  return __uint_as_float(((unsigned int)h) << 16);
}
__device__ __forceinline__ void split3(float f, unsigned short& h,
                                       unsigned short& m, unsigned short& l) {
  h = bf16rn(f); float r1 = f - bf2f(h);          // 3x8 mantissa bits = fp32
  m = bf16rn(r1); float r2 = r1 - bf2f(m);
  l = bf16rn(r2);
}

// ---------------- single fused kernel, MFMA bf16x3 fp32-emulated GEMM --------
// LDS map (f4 units, lds4[4608] = 72 KB):
//   A (x bf16, 3 levels): [0..3071]   level L at L*1024 + row*16 + (g ^ (row&15))
//   B (v bf16, 3 levels): [3072..4607] level L at 3072 + L*512 + p*16 + (g^(p&15))
//   stat scratch overlays B pre-build; park (1024 f4) overlays A post-GEMM.
__global__ __launch_bounds__(512, 4)
void fused_kernel(const float* __restrict__ x,
                  const float* __restrict__ weight,
                  const float* __restrict__ bias,
                  float* __restrict__ out) {
  __shared__ float4 lds4[4608];
  __shared__ double psum[96];
  __shared__ float x2A[64], fbA[64];
  __shared__ float bwA[32], iaA[32], soA[32];

  float* const scpf = reinterpret_cast<float*>(lds4 + 3072);        // 6*512 f32
  float* const scxf = reinterpret_cast<float*>(lds4 + 3072 + 768);  // 4*512 f32
  ushort4* const ldsu4 = reinterpret_cast<ushort4*>(lds4);
  const bf8* const ldsb = reinterpret_cast<const bf8*>(lds4);

  const int tid = threadIdx.x;
  const int b0 = blockIdx.x * BT;
  const int p0 = blockIdx.y * PT;
  const int rr = tid >> 5;              // 0..15: row within 16-row group
  const int cc = tid & 31;              // f4 column chunk

  // ---- global loads (coalesced: 32 lanes span a 512B row)
  float4 xv[4], wv[2], bv[2];
#pragma unroll
  for (int q = 0; q < 4; ++q)
    xv[q] = *reinterpret_cast<const float4*>(x + (size_t)(b0 + 16 * q + rr) * Dn + cc * 4);
#pragma unroll
  for (int q = 0; q < 2; ++q) {
    wv[q] = *reinterpret_cast<const float4*>(weight + (size_t)(p0 + 16 * q + rr) * Dn + cc * 4);
    bv[q] = *reinterpret_cast<const float4*>(bias + (size_t)(p0 + 16 * q + rr) * Dn + cc * 4);
  }

  // ---- phase 1: x -> 3-level bf16 into A region; f32 stat partials to scratch
#pragma unroll
  for (int q = 0; q < 4; ++q) {
    const int r = 16 * q + rr;
    float4 v = xv[q];
    float a[4] = {v.x, v.y, v.z, v.w};
    unsigned short h[4], m[4], lo[4];
#pragma unroll
    for (int e = 0; e < 4; ++e) split3(a[e], h[e], m[e], lo[e]);
    const int base = ((r * 16 + ((cc >> 1) ^ (r & 15))) << 1) + (cc & 1);
    ldsu4[base]            = make_ushort4(h[0], h[1], h[2], h[3]);
    ldsu4[2048 + base]     = make_ushort4(m[0], m[1], m[2], m[3]);
    ldsu4[4096 + base]     = make_ushort4(lo[0], lo[1], lo[2], lo[3]);
    scxf[q * 512 + tid] = fmaf(a[0], a[0], fmaf(a[1], a[1], fmaf(a[2], a[2], a[3] * a[3])));
  }
#pragma unroll
  for (int q = 0; q < 2; ++q) {
    float4 w = wv[q], b = bv[q];
    scpf[(q * 3 + 0) * 512 + tid] = fmaf(b.x, b.x, fmaf(b.y, b.y, fmaf(b.z, b.z, b.w * b.w)));
    scpf[(q * 3 + 1) * 512 + tid] = fmaf(b.x, w.x, fmaf(b.y, w.y, fmaf(b.z, w.z, b.w * w.w)));
    scpf[(q * 3 + 2) * 512 + tid] = fmaf(w.x, w.x, fmaf(w.y, w.y, fmaf(w.z, w.z, w.w * w.w)));
  }
  __syncthreads();

  // ---- phase 2: trees (rotated f4 reads, f64 accumulate)
  if (tid < 96) {
    const int row = tid / 3;
    const int val = tid - 3 * row;
    const float4* base = reinterpret_cast<const float4*>(scpf) +
                         ((row >> 4) * 3 + val) * 128 + (row & 15) * 8;
    double s = 0.0;
#pragma unroll
    for (int jj = 0; jj < 8; ++jj) {
      float4 f = base[(jj + tid) & 7];
      s += (double)f.x + (double)f.y + (double)f.z + (double)f.w;
    }
    psum[tid] = s;
  } else if (tid >= 256 && tid < 320) {
    const int r = tid - 256;
    const float4* base = reinterpret_cast<const float4*>(scxf) +
                         (r >> 4) * 128 + (r & 15) * 8;
    double s = 0.0;
#pragma unroll
    for (int jj = 0; jj < 8; ++jj) {
      float4 f = base[(jj + tid) & 7];
      s += (double)f.x + (double)f.y + (double)f.z + (double)f.w;
    }
    x2A[r] = (float)s;
    fbA[r] = (float)(2.0 / (1.0 - s));
  }
  __syncthreads();

  // ---- phase 3: v-build (f64 cancellation island) + 3-level bf16 B-tiles
#pragma unroll
  for (int q = 0; q < 2; ++q) {
    const int r = 16 * q + rr;
    double nb2 = psum[3 * r + 0];
    double bwd = psum[3 * r + 1];
    double w2  = psum[3 * r + 2];
    double norm = sqrt(nb2);
    if (norm < 1e-15) norm = 1e-15;
    double scl = (norm > (double)MAXN) ? (double)MAXN / norm : 1.0;
    double p2 = nb2 * scl * scl;
    const float cxf = (float)(1.0 - p2);
    const float bwf = (float)(scl * bwd);
    const float k2f = 2.0f * bwf * (float)scl;
    float4 w = wv[q], b = bv[q];
    float vvv[4];
    vvv[0] = fmaf(cxf, w.x, k2f * b.x);
    vvv[1] = fmaf(cxf, w.y, k2f * b.y);
    vvv[2] = fmaf(cxf, w.z, k2f * b.z);
    vvv[3] = fmaf(cxf, w.w, k2f * b.w);
    unsigned short h[4], m[4], lo[4];
#pragma unroll
    for (int e = 0; e < 4; ++e) split3(vvv[e], h[e], m[e], lo[e]);
    const int base = ((3072 + r * 16 + ((cc >> 1) ^ (r & 15))) << 1) + (cc & 1);
    ldsu4[base]        = make_ushort4(h[0], h[1], h[2], h[3]);
    ldsu4[1024 + base] = make_ushort4(m[0], m[1], m[2], m[3]);   // +512 f4 = +1024 u4
    ldsu4[2048 + base] = make_ushort4(lo[0], lo[1], lo[2], lo[3]);
    if (cc == 0) {
      float an = cxf * sqrtf((float)w2);
      if (an < 1e-15f) an = 1e-15f;
      bwA[r] = bwf;
      iaA[r] = 1.0f / an;
      soA[r] = 2.0f / cxf * an;           // lambda_p * a_norm
    }
  }
  __syncthreads();

  // ---- phase 4: MFMA GEMM. wave = (strip 0..3, khalf 0..1); 24 MFMA/wave.
  const int wid = tid >> 6;
  const int l = tid & 63;
  const int strip = wid & 3;
  const int khalf = wid >> 2;
  const int arow = strip * 16 + (l & 15);
  const int prow0 = l & 15, prow1 = 16 + (l & 15);
  const int kgrp = l >> 4;
  f32x4 acc0 = {0.f, 0.f, 0.f, 0.f}, acc1 = {0.f, 0.f, 0.f, 0.f};
#pragma unroll
  for (int kc2 = 0; kc2 < 2; ++kc2) {
    const int ga = ((khalf * 2 + kc2) * 4 + kgrp) ^ (l & 15);  // row&15 == l&15
    bf8 aH = ldsb[0 * 1024 + arow * 16 + ga];
    bf8 aM = ldsb[1 * 1024 + arow * 16 + ga];
    bf8 aL = ldsb[2 * 1024 + arow * 16 + ga];
    bf8 b0H = ldsb[3072 + 0 * 512 + prow0 * 16 + ga];
    bf8 b0M = ldsb[3072 + 1 * 512 + prow0 * 16 + ga];
    bf8 b0L = ldsb[3072 + 2 * 512 + prow0 * 16 + ga];
    bf8 b1H = ldsb[3072 + 0 * 512 + prow1 * 16 + ga];
    bf8 b1M = ldsb[3072 + 1 * 512 + prow1 * 16 + ga];
    bf8 b1L = ldsb[3072 + 2 * 512 + prow1 * 16 + ga];
    // 6 products, small-to-large: hh + hm + mh + mm + hl + lh ~ full fp32
    acc0 = __builtin_amdgcn_mfma_f32_16x16x32_bf16(aL, b0H, acc0, 0, 0, 0);
    acc0 = __builtin_amdgcn_mfma_f32_16x16x32_bf16(aH, b0L, acc0, 0, 0, 0);
    acc0 = __builtin_amdgcn_mfma_f32_16x16x32_bf16(aM, b0M, acc0, 0, 0, 0);
    acc0 = __builtin_amdgcn_mfma_f32_16x16x32_bf16(aM, b0H, acc0, 0, 0, 0);
    acc0 = __builtin_amdgcn_mfma_f32_16x16x32_bf16(aH, b0M, acc0, 0, 0, 0);
    acc0 = __builtin_amdgcn_mfma_f32_16x16x32_bf16(aH, b0H, acc0, 0, 0, 0);
    acc1 = __builtin_amdgcn_mfma_f32_16x16x32_bf16(aL, b1H, acc1, 0, 0, 0);
    acc1 = __builtin_amdgcn_mfma_f32_16x16x32_bf16(aH, b1L, acc1, 0, 0, 0);
    acc1 = __builtin_amdgcn_mfma_f32_16x16x32_bf16(aM, b1M, acc1, 0, 0, 0);
    acc1 = __builtin_amdgcn_mfma_f32_16x16x32_bf16(aM, b1H, acc1, 0, 0, 0);
    acc1 = __builtin_amdgcn_mfma_f32_16x16x32_bf16(aH, b1M, acc1, 0, 0, 0);
    acc1 = __builtin_amdgcn_mfma_f32_16x16x32_bf16(aH, b1H, acc1, 0, 0, 0);
  }
  __syncthreads();

  // ---- phase 5: both k-teams park into dead A region [khalf][strip][t][lane]
  lds4[khalf * 512 + strip * 128 + 0 * 64 + l] =
      make_float4(acc0[0], acc0[1], acc0[2], acc0[3]);
  lds4[khalf * 512 + strip * 128 + 1 * 64 + l] =
      make_float4(acc1[0], acc1[1], acc1[2], acc1[3]);
  __syncthreads();

  // ---- phase 6: distributed merge + epilogue (all 512 threads, 4 outputs each)
  {
    const int es = tid >> 7;              // strip
    const int et = (tid >> 6) & 1;        // p-tile
    const int el = tid & 63;              // lane
    float4 pa = lds4[es * 128 + et * 64 + el];
    float4 pb = lds4[512 + es * 128 + et * 64 + el];
    float s4[4] = {pa.x + pb.x, pa.y + pb.y, pa.z + pb.z, pa.w + pb.w};
    const int pl = et * 16 + (el & 15);   // local p (C/D: col = lane&15)
    const float bwp = bwA[pl], iap = iaA[pl], sop = soA[pl];
#pragma unroll
    for (int reg = 0; reg < 4; ++reg) {
      const int brl = es * 16 + (el >> 4) * 4 + reg;   // C/D: row=(lane>>4)*4+reg
      const float x2i = x2A[brl];
      const float fbi = fbA[brl];
      float X = fmaf(-(1.0f + x2i), bwp, s4[reg]);     // <x,v> - (1+x2)*bw
      float arg = X * fbi * iap;                       // Mobius denominator cancels
      float aa = fabsf(arg);
      float argc;
      if (aa <= CLAMPV - 0.35f) {
        argc = aa;                                     // smooth_clamp == identity
      } else if (aa >= CLAMPV + 0.35f) {
        argc = CLAMPV;                                 // fully clamped (exact)
      } else {
        float z = SMOOTH * (aa - CLAMPV);              // band: softplus correction
        float sp = (fmaxf(z, 0.0f) + log1pf(__expf(-fabsf(z)))) * (1.0f / SMOOTH);
        argc = aa - sp;
      }
      float r = __logf(argc + sqrtf(fmaf(argc, argc, 1.0f)));  // asinh, z>=0
      out[(size_t)(b0 + brl) * Pn + p0 + pl] = copysignf(sop * r, arg);
    }
  }
}

extern "C" void kernel_launch(void* const* d_in, const int* in_sizes, int n_in,
                              void* d_out, int out_size, void* d_ws, size_t ws_size,
                              hipStream_t stream) {
  const float* x = (const float*)d_in[0];
  const float* w = (const float*)d_in[1];
  const float* bias = (const float*)d_in[2];
  float* out = (float*)d_out;

  hipLaunchKernelGGL(fused_kernel, dim3(Bn / BT, Pn / PT), dim3(512), 0, stream,
                     x, w, bias, out);
}

// Round 16
// 13.050 us; speedup vs baseline: 1.2945x; 1.0790x over previous
//
#include <hip/hip_runtime.h>
#include <math.h>

namespace {
constexpr int Bn = 8192, Pn = 128, Dn = 128;
constexpr int BT = 64, PT = 32;                   // block tile: 64 b x 32 p
constexpr float MAXN = 1.0f - 1e-5f;              // (1-PROJ_EPS)/sqrt(c)
constexpr float CLAMPV = 16.63553233343869f;      // log(2/eps32)
constexpr float SMOOTH = 50.0f;
}

typedef short bf8 __attribute__((ext_vector_type(8)));       // MFMA A/B frag (8 bf16)
typedef unsigned short u16x8 __attribute__((ext_vector_type(8)));
typedef float f32x4 __attribute__((ext_vector_type(4)));     // MFMA C/D frag

__device__ __forceinline__ unsigned short bf16rn(float f) {
  unsigned int u = __float_as_uint(f);
  u = u + 0x7fffu + ((u >> 16) & 1u);             // round-to-nearest-even
  return (unsigned short)(u >> 16);
}
__device__ __forceinline__ float bf2f(unsigned short h) {
  return __uint_as_float(((unsigned int)h) << 16);
}
__device__ __forceinline__ void split3(float f, unsigned short& h,
                                       unsigned short& m, unsigned short& l) {
  h = bf16rn(f); float r1 = f - bf2f(h);          // 3x8 mantissa bits ~ fp32
  m = bf16rn(r1); float r2 = r1 - bf2f(m);
  l = bf16rn(r2);
}

// ---------------- single fused kernel: MFMA bf16x3, wave-owns-quadrant -------
// LDS (16B slots, 4608 = 72 KB):
//   A (x):  level L at L*1024 + row*16 + (g ^ (row&15)),  row 0..63, g 0..15
//   B (v):  level L at 3072 + L*512 + p*16 + (g ^ (p&15)), p 0..31
//   stat scratch (8 KB f32) overlays B pre-build. 3 barriers total.
__global__ __launch_bounds__(512, 4)
void fused_kernel(const float* __restrict__ x,
                  const float* __restrict__ weight,
                  const float* __restrict__ bias,
                  float* __restrict__ out) {
  __shared__ float4 lds4[4608];
  __shared__ double psum[96];
  __shared__ float x2A[64], fbA[64];
  __shared__ float bwA[32], iaA[32], soA[32];

  u16x8* const LU = reinterpret_cast<u16x8*>(lds4);
  const bf8* const LB = reinterpret_cast<const bf8*>(lds4);
  float* const scp = reinterpret_cast<float*>(lds4 + 3072);  // [stat][seg16][row32]
  float* const scx = scp + 1536;                             // [seg8][row64]

  const int tid = threadIdx.x;
  const int b0 = blockIdx.x * BT;
  const int p0 = blockIdx.y * PT;

  // ---- phase 1a: x -> 3-level bf16 (2 granules/thread, 16B writes) + x2 partial
  const int rA = tid >> 3, sA = tid & 7;          // row 0..63, 16-elem segment 0..7
  {
    float xe[16];
    const float* xr = x + (size_t)(b0 + rA) * Dn + sA * 16;
#pragma unroll
    for (int j = 0; j < 4; ++j) {
      float4 q = *reinterpret_cast<const float4*>(xr + 4 * j);
      xe[4 * j] = q.x; xe[4 * j + 1] = q.y; xe[4 * j + 2] = q.z; xe[4 * j + 3] = q.w;
    }
    float s2 = 0.f;
#pragma unroll
    for (int e = 0; e < 16; ++e) s2 = fmaf(xe[e], xe[e], s2);
    scx[sA * 64 + rA] = s2;                       // transposed: tree reads stride-1
    const int sw = rA & 15;
#pragma unroll
    for (int g = 0; g < 2; ++g) {
      u16x8 H, M, L;
#pragma unroll
      for (int e = 0; e < 8; ++e) {
        unsigned short h, m, l;
        split3(xe[g * 8 + e], h, m, l);
        H[e] = h; M[e] = m; L[e] = l;
      }
      const int slot = rA * 16 + ((2 * sA + g) ^ sw);
      LU[slot] = H;
      LU[1024 + slot] = M;
      LU[2048 + slot] = L;
    }
  }
  // ---- phase 1b: w/bias loads (1 granule/thread) + stat partials
  const int rP = tid >> 4, sP = tid & 15;         // p-row 0..31, granule 0..15
  float we[8], be[8];
  {
    const float* wr = weight + (size_t)(p0 + rP) * Dn + sP * 8;
    const float* br = bias + (size_t)(p0 + rP) * Dn + sP * 8;
#pragma unroll
    for (int j = 0; j < 2; ++j) {
      float4 qw = *reinterpret_cast<const float4*>(wr + 4 * j);
      float4 qb = *reinterpret_cast<const float4*>(br + 4 * j);
      we[4 * j] = qw.x; we[4 * j + 1] = qw.y; we[4 * j + 2] = qw.z; we[4 * j + 3] = qw.w;
      be[4 * j] = qb.x; be[4 * j + 1] = qb.y; be[4 * j + 2] = qb.z; be[4 * j + 3] = qb.w;
    }
    float nb2 = 0.f, bwd = 0.f, w2 = 0.f;
#pragma unroll
    for (int e = 0; e < 8; ++e) {
      nb2 = fmaf(be[e], be[e], nb2);
      bwd = fmaf(be[e], we[e], bwd);
      w2  = fmaf(we[e], we[e], w2);
    }
    scp[0 * 512 + sP * 32 + rP] = nb2;
    scp[1 * 512 + sP * 32 + rP] = bwd;
    scp[2 * 512 + sP * 32 + rP] = w2;
  }
  __syncthreads();

  // ---- phase 2: trees (conflict-light scalar reads, f64 accumulate)
  if (tid < 96) {
    const int stat = tid >> 5, row = tid & 31;
    double s = 0.0;
#pragma unroll
    for (int j = 0; j < 16; ++j) s += (double)scp[stat * 512 + j * 32 + row];
    psum[stat * 32 + row] = s;
  } else if (tid >= 128 && tid < 192) {
    const int r = tid - 128;
    double s = 0.0;
#pragma unroll
    for (int j = 0; j < 8; ++j) s += (double)scx[j * 64 + r];
    x2A[r] = (float)s;
    fbA[r] = (float)(2.0 / (1.0 - s));
  }
  __syncthreads();

  // ---- phase 3: v-build (f64 cancellation island) + 3-level bf16 B writes
  {
    double nb2 = psum[rP];
    double bwd = psum[32 + rP];
    double w2  = psum[64 + rP];
    double norm = sqrt(nb2);
    if (norm < 1e-15) norm = 1e-15;
    double scl = (norm > (double)MAXN) ? (double)MAXN / norm : 1.0;
    double p2 = nb2 * scl * scl;
    const float cxf = (float)(1.0 - p2);
    const float bwf = (float)(scl * bwd);
    const float k2f = 2.0f * bwf * (float)scl;
    u16x8 VH, VM, VL;
#pragma unroll
    for (int e = 0; e < 8; ++e) {
      float v = fmaf(cxf, we[e], k2f * be[e]);
      unsigned short h, m, l;
      split3(v, h, m, l);
      VH[e] = h; VM[e] = m; VL[e] = l;
    }
    const int slot = 3072 + rP * 16 + (sP ^ (rP & 15));
    LU[slot] = VH;
    LU[512 + slot] = VM;
    LU[1024 + slot] = VL;
    if (sP == 0) {
      float an = cxf * sqrtf((float)w2);
      if (an < 1e-15f) an = 1e-15f;
      bwA[rP] = bwf;
      iaA[rP] = 1.0f / an;
      soA[rP] = 2.0f / cxf * an;                  // lambda_p * a_norm
    }
  }
  __syncthreads();

  // ---- phase 4: full-K MFMA; wave = (strip 0..3) x (ptile 0..1); 24 MFMA
  const int wid = tid >> 6, l = tid & 63;
  const int strip = wid & 3, ptile = wid >> 2;
  const int l15 = l & 15;
  const int arow = strip * 16 + l15;
  const int prow = ptile * 16 + l15;
  const int kg = l >> 4;
  f32x4 acc = {0.f, 0.f, 0.f, 0.f};
#pragma unroll
  for (int kc = 0; kc < 4; ++kc) {
    const int ga = (kc * 4 + kg) ^ l15;
    bf8 aH = LB[arow * 16 + ga];
    bf8 aM = LB[1024 + arow * 16 + ga];
    bf8 aL = LB[2048 + arow * 16 + ga];
    bf8 vH = LB[3072 + prow * 16 + ga];
    bf8 vM = LB[3584 + prow * 16 + ga];
    bf8 vL = LB[4096 + prow * 16 + ga];
    // 6 products, small-to-large: ~fp32-accurate
    acc = __builtin_amdgcn_mfma_f32_16x16x32_bf16(aL, vH, acc, 0, 0, 0);
    acc = __builtin_amdgcn_mfma_f32_16x16x32_bf16(aH, vL, acc, 0, 0, 0);
    acc = __builtin_amdgcn_mfma_f32_16x16x32_bf16(aM, vM, acc, 0, 0, 0);
    acc = __builtin_amdgcn_mfma_f32_16x16x32_bf16(aM, vH, acc, 0, 0, 0);
    acc = __builtin_amdgcn_mfma_f32_16x16x32_bf16(aH, vM, acc, 0, 0, 0);
    acc = __builtin_amdgcn_mfma_f32_16x16x32_bf16(aH, vH, acc, 0, 0, 0);
  }

  // ---- epilogue (no barrier: stats barrier'd at phase 3; acc is private)
  {
    const int pl = ptile * 16 + l15;              // C/D: col = lane&15
    const float bwp = bwA[pl], iap = iaA[pl], sop = soA[pl];
#pragma unroll
    for (int reg = 0; reg < 4; ++reg) {
      const int brl = strip * 16 + (l >> 4) * 4 + reg;  // C/D: row=(lane>>4)*4+reg
      const float x2i = x2A[brl];
      const float fbi = fbA[brl];
      float X = fmaf(-(1.0f + x2i), bwp, acc[reg]);     // <x,v> - (1+x2)*bw
      float arg = X * fbi * iap;                        // Mobius denominator cancels
      float aa = fabsf(arg);
      float argc;
      if (aa <= CLAMPV - 0.35f) {
        argc = aa;                                      // smooth_clamp == identity
      } else if (aa >= CLAMPV + 0.35f) {
        argc = CLAMPV;                                  // fully clamped (exact)
      } else {
        float z = SMOOTH * (aa - CLAMPV);               // band: softplus correction
        float sp = (fmaxf(z, 0.0f) + log1pf(__expf(-fabsf(z)))) * (1.0f / SMOOTH);
        argc = aa - sp;
      }
      float r = __logf(argc + sqrtf(fmaf(argc, argc, 1.0f)));  // asinh, z>=0
      out[(size_t)(b0 + brl) * Pn + p0 + pl] = copysignf(sop * r, arg);
    }
  }
}

extern "C" void kernel_launch(void* const* d_in, const int* in_sizes, int n_in,
                              void* d_out, int out_size, void* d_ws, size_t ws_size,
                              hipStream_t stream) {
  const float* x = (const float*)d_in[0];
  const float* w = (const float*)d_in[1];
  const float* bias = (const float*)d_in[2];
  float* out = (float*)d_out;

  hipLaunchKernelGGL(fused_kernel, dim3(Bn / BT, Pn / PT), dim3(512), 0, stream,
                     x, w, bias, out);
}

// Round 18
// 12.424 us; speedup vs baseline: 1.3597x; 1.0504x over previous
//
#include <hip/hip_runtime.h>
#include <hip/hip_bf16.h>
#include <math.h>

namespace {
constexpr int Bn = 8192, Pn = 128, Dn = 128;
constexpr int BT = 64, PT = 32;                   // block tile: 64 b x 32 p
constexpr float MAXN = 1.0f - 1e-5f;              // (1-PROJ_EPS)/sqrt(c)
constexpr float CLAMPV = 16.63553233343869f;      // log(2/eps32)
constexpr float SMOOTH = 50.0f;
}

typedef short bf8 __attribute__((ext_vector_type(8)));       // MFMA A/B frag (8 bf16)
typedef float f32x4 __attribute__((ext_vector_type(4)));     // MFMA C/D frag

__device__ __forceinline__ unsigned int bits2(__hip_bfloat162 v) {
  unsigned int u;
  __builtin_memcpy(&u, &v, 4);
  return u;
}

// pairwise 3-level bf16 split via v_cvt_pk_bf16_f32 (RNE, residuals exact fp32)
__device__ __forceinline__ void split3_pair(float f0, float f1,
                                            unsigned int& H, unsigned int& M,
                                            unsigned int& L) {
  __hip_bfloat162 h2 = __float22bfloat162_rn(make_float2(f0, f1));
  float2 fh = __bfloat1622float2(h2);
  __hip_bfloat162 m2 = __float22bfloat162_rn(make_float2(f0 - fh.x, f1 - fh.y));
  float2 fm = __bfloat1622float2(m2);
  __hip_bfloat162 l2 = __float22bfloat162_rn(
      make_float2((f0 - fh.x) - fm.x, (f1 - fh.y) - fm.y));
  H = bits2(h2);
  M = bits2(m2);
  L = bits2(l2);
}

// ---------------- single fused kernel: MFMA bf16x3, wave-owns-quadrant -------
// LDS (16B slots, 4608 = 72 KB):
//   A (x):  level Lv at Lv*1024 + row*16 + (g ^ (row&15)),  row 0..63, g 0..15
//   B (v):  level Lv at 3072 + Lv*512 + p*16 + (g ^ (p&15)), p 0..31
//   stat scratch overlays B pre-build. 3 barriers total.
__global__ __launch_bounds__(512, 4)
void fused_kernel(const float* __restrict__ x,
                  const float* __restrict__ weight,
                  const float* __restrict__ bias,
                  float* __restrict__ out) {
  __shared__ float4 lds4[4608];
  __shared__ float psumF[96];
  __shared__ float opxA[64], fbA[64];
  __shared__ float nbwA[32], iaA[32], soA[32];

  uint4* const L32 = reinterpret_cast<uint4*>(lds4);
  const bf8* const LB = reinterpret_cast<const bf8*>(lds4);
  float* const scp = reinterpret_cast<float*>(lds4 + 3072);  // [stat][seg16 s33][row32]
  float* const scx = scp + 3 * 528;                          // [seg8 s65][row64]

  const int tid = threadIdx.x;
  const int b0 = blockIdx.x * BT;
  const int p0 = blockIdx.y * PT;
  const int rA = tid >> 3, sA = tid & 7;          // x: row 0..63, 16-elem segment
  const int rP = tid >> 4, sP = tid & 15;         // w/b: p-row 0..31, 8-elem granule

  // ---- all global loads issued up front (w/b latency hides under x split)
  float xe[16], we[8], be[8];
  {
    const float* xr = x + (size_t)(b0 + rA) * Dn + sA * 16;
    const float* wr = weight + (size_t)(p0 + rP) * Dn + sP * 8;
    const float* br = bias + (size_t)(p0 + rP) * Dn + sP * 8;
#pragma unroll
    for (int j = 0; j < 4; ++j) {
      float4 q = *reinterpret_cast<const float4*>(xr + 4 * j);
      xe[4 * j] = q.x; xe[4 * j + 1] = q.y; xe[4 * j + 2] = q.z; xe[4 * j + 3] = q.w;
    }
#pragma unroll
    for (int j = 0; j < 2; ++j) {
      float4 qw = *reinterpret_cast<const float4*>(wr + 4 * j);
      float4 qb = *reinterpret_cast<const float4*>(br + 4 * j);
      we[4 * j] = qw.x; we[4 * j + 1] = qw.y; we[4 * j + 2] = qw.z; we[4 * j + 3] = qw.w;
      be[4 * j] = qb.x; be[4 * j + 1] = qb.y; be[4 * j + 2] = qb.z; be[4 * j + 3] = qb.w;
    }
  }

  // ---- phase 1a: x -> 3-level bf16 (packed cvt), x2 partial
  {
    float s2 = 0.f;
#pragma unroll
    for (int e = 0; e < 16; ++e) s2 = fmaf(xe[e], xe[e], s2);
    scx[sA * 65 + rA] = s2;
    const int sw = rA & 15;
#pragma unroll
    for (int g = 0; g < 2; ++g) {
      unsigned int HW[4], MW[4], LW[4];
#pragma unroll
      for (int pp = 0; pp < 4; ++pp)
        split3_pair(xe[g * 8 + 2 * pp], xe[g * 8 + 2 * pp + 1],
                    HW[pp], MW[pp], LW[pp]);
      const int slot = rA * 16 + ((2 * sA + g) ^ sw);
      L32[slot]        = make_uint4(HW[0], HW[1], HW[2], HW[3]);
      L32[1024 + slot] = make_uint4(MW[0], MW[1], MW[2], MW[3]);
      L32[2048 + slot] = make_uint4(LW[0], LW[1], LW[2], LW[3]);
    }
  }
  // ---- phase 1b: w/b stat partials (f32; p-side has no cancellation)
  {
    float nb2 = 0.f, bwd = 0.f, w2 = 0.f;
#pragma unroll
    for (int e = 0; e < 8; ++e) {
      nb2 = fmaf(be[e], be[e], nb2);
      bwd = fmaf(be[e], we[e], bwd);
      w2  = fmaf(we[e], we[e], w2);
    }
    scp[0 * 528 + sP * 33 + rP] = nb2;
    scp[1 * 528 + sP * 33 + rP] = bwd;
    scp[2 * 528 + sP * 33 + rP] = w2;
  }
  __syncthreads();

  // ---- phase 2: trees
  if (tid < 96) {
    const int stat = tid >> 5, row = tid & 31;
    float s = 0.f;
#pragma unroll
    for (int j = 0; j < 16; ++j) s += scp[stat * 528 + j * 33 + row];
    psumF[stat * 32 + row] = s;
  } else if (tid >= 128 && tid < 192) {
    const int r = tid - 128;
    double s = 0.0;                               // x-side: f64 (1-x2 ~ 2e-5)
#pragma unroll
    for (int j = 0; j < 8; ++j) s += (double)scx[j * 65 + r];
    opxA[r] = (float)(1.0 + s);
    fbA[r] = (float)(2.0 / (1.0 - s));
  }
  __syncthreads();

  // ---- phase 3: v-build (f64 cancellation island) + 3-level bf16 B writes
  {
    double nb2 = (double)psumF[rP];
    double bwd = (double)psumF[32 + rP];
    float w2   = psumF[64 + rP];
    double norm = sqrt(nb2);
    if (norm < 1e-15) norm = 1e-15;
    double scl = (norm > (double)MAXN) ? (double)MAXN / norm : 1.0;
    double p2 = nb2 * scl * scl;
    const float cxf = (float)(1.0 - p2);
    const float bwf = (float)(scl * bwd);
    const float k2f = 2.0f * bwf * (float)scl;
    unsigned int VH[4], VM[4], VL[4];
#pragma unroll
    for (int pp = 0; pp < 4; ++pp) {
      float v0 = fmaf(cxf, we[2 * pp], k2f * be[2 * pp]);
      float v1 = fmaf(cxf, we[2 * pp + 1], k2f * be[2 * pp + 1]);
      split3_pair(v0, v1, VH[pp], VM[pp], VL[pp]);
    }
    const int slot = 3072 + rP * 16 + (sP ^ (rP & 15));
    L32[slot]        = make_uint4(VH[0], VH[1], VH[2], VH[3]);
    L32[512 + slot]  = make_uint4(VM[0], VM[1], VM[2], VM[3]);
    L32[1024 + slot] = make_uint4(VL[0], VL[1], VL[2], VL[3]);
    if (sP == 0) {
      float an = cxf * sqrtf(w2);
      if (an < 1e-15f) an = 1e-15f;
      nbwA[rP] = -bwf;
      iaA[rP] = 1.0f / an;
      soA[rP] = 2.0f / cxf * an;                  // lambda_p * a_norm
    }
  }
  __syncthreads();

  // ---- phase 4: full-K MFMA; wave = (strip 0..3) x (ptile 0..1); 24 MFMA
  const int wid = tid >> 6, l = tid & 63;
  const int strip = wid & 3, ptile = wid >> 2;
  const int l15 = l & 15;
  const int arow = strip * 16 + l15;
  const int prow = ptile * 16 + l15;
  const int kg = l >> 4;
  f32x4 acc = {0.f, 0.f, 0.f, 0.f};
#pragma unroll
  for (int kc = 0; kc < 4; ++kc) {
    const int ga = (kc * 4 + kg) ^ l15;
    bf8 aH = LB[arow * 16 + ga];
    bf8 aM = LB[1024 + arow * 16 + ga];
    bf8 aL = LB[2048 + arow * 16 + ga];
    bf8 vH = LB[3072 + prow * 16 + ga];
    bf8 vM = LB[3584 + prow * 16 + ga];
    bf8 vL = LB[4096 + prow * 16 + ga];
    // 6 products, small-to-large: ~fp32-accurate
    acc = __builtin_amdgcn_mfma_f32_16x16x32_bf16(aL, vH, acc, 0, 0, 0);
    acc = __builtin_amdgcn_mfma_f32_16x16x32_bf16(aH, vL, acc, 0, 0, 0);
    acc = __builtin_amdgcn_mfma_f32_16x16x32_bf16(aM, vM, acc, 0, 0, 0);
    acc = __builtin_amdgcn_mfma_f32_16x16x32_bf16(aM, vH, acc, 0, 0, 0);
    acc = __builtin_amdgcn_mfma_f32_16x16x32_bf16(aH, vM, acc, 0, 0, 0);
    acc = __builtin_amdgcn_mfma_f32_16x16x32_bf16(aH, vH, acc, 0, 0, 0);
  }

  // ---- epilogue (no barrier; acc private, stat arrays barrier-protected)
  {
    const int pl = ptile * 16 + l15;              // C/D: col = lane&15
    const float nbw = nbwA[pl], iap = iaA[pl], sop = soA[pl];
#pragma unroll
    for (int reg = 0; reg < 4; ++reg) {
      const int brl = strip * 16 + (l >> 4) * 4 + reg;  // C/D: row=(lane>>4)*4+reg
      const float opx = opxA[brl];
      const float fbi = fbA[brl];
      float X = fmaf(opx, nbw, acc[reg]);               // <x,v> - (1+x2)*bw
      float arg = X * fbi * iap;                        // Mobius denominator cancels
      float aa = fabsf(arg);
      float argc;
      if (aa <= CLAMPV - 0.35f) {
        argc = aa;                                      // smooth_clamp == identity
      } else if (aa >= CLAMPV + 0.35f) {
        argc = CLAMPV;                                  // fully clamped (exact)
      } else {
        float z = SMOOTH * (aa - CLAMPV);               // band: softplus correction
        float sp = (fmaxf(z, 0.0f) + log1pf(__expf(-fabsf(z)))) * (1.0f / SMOOTH);
        argc = aa - sp;
      }
      float r = __logf(argc + sqrtf(fmaf(argc, argc, 1.0f)));  // asinh, z>=0
      out[(size_t)(b0 + brl) * Pn + p0 + pl] = copysignf(sop * r, arg);
    }
  }
}

extern "C" void kernel_launch(void* const* d_in, const int* in_sizes, int n_in,
                              void* d_out, int out_size, void* d_ws, size_t ws_size,
                              hipStream_t stream) {
  const float* x = (const float*)d_in[0];
  const float* w = (const float*)d_in[1];
  const float* bias = (const float*)d_in[2];
  float* out = (float*)d_out;

  hipLaunchKernelGGL(fused_kernel, dim3(Bn / BT, Pn / PT), dim3(512), 0, stream,
                     x, w, bias, out);
}